// Round 7
// baseline (70.329 us; speedup 1.0000x reference)
//
#include <hip/hip_runtime.h>
#include <stdint.h>

typedef unsigned short u16;
typedef unsigned int u32;
typedef __attribute__((ext_vector_type(8))) __bf16 bf16x8;
typedef __attribute__((ext_vector_type(4))) float f32x4;

#define B_TOT   32768
#define T_SEQ   96
#define D_IN    7
#define K_LIN   288   // H*T
#define N_LIN   672   // O*T
#define N_PAD   768   // padded N so 128-wide tiles need no load guards

#define LOG2E      1.4426950408889634f
#define TWO_LOG2E  2.8853900817779268f

// ---------- helpers ----------
__device__ __forceinline__ u16 f2bf(float f) {
  u32 u = __builtin_bit_cast(u32, f);
  u += 0x7fffu + ((u >> 16) & 1u);   // RNE; inputs finite
  return (u16)(u >> 16);
}
// z' = z*log2e prescaled:  sigmoid(z) = rcp(1 + 2^(-z'))
__device__ __forceinline__ float sig2(float zp) {
  return __builtin_amdgcn_rcpf(1.0f + __builtin_amdgcn_exp2f(-zp));
}
// z'' = 2*log2e*z prescaled:  tanh(z) = 1 - 2*rcp(1 + 2^(z''))
__device__ __forceinline__ float tanh2(float zpp) {
  return 1.0f - 2.0f * __builtin_amdgcn_rcpf(1.0f + __builtin_amdgcn_exp2f(zpp));
}
// broadcast quad-lane Q's value to all 4 lanes of the quad (DPP, full-rate VALU)
template<int Q>
__device__ __forceinline__ float qbcast(float v) {
  int i = __builtin_bit_cast(int, v);
  i = __builtin_amdgcn_update_dpp(0, i, Q * 0x55, 0xF, 0xF, true);
  return __builtin_bit_cast(float, i);
}

// ---------- kernel 1: pad/convert W_lin -> bf16, k-permuted to j-major ----------
// Bw[n][j*96+t] = Wlin[n][t*3+j]  (matches lstm's j-major hs layout)
__global__ __launch_bounds__(256) void convert_kernel(
    const float* __restrict__ Wlin, const float* __restrict__ blin,
    u16* __restrict__ Bw, float* __restrict__ biasp)
{
  int i = blockIdx.x * 256 + threadIdx.x;
  if (i < N_PAD * K_LIN) {
    int n = i / K_LIN;
    int kk = i - n * K_LIN;
    int jm = kk / T_SEQ;          // 0..2
    int tm = kk - jm * T_SEQ;     // 0..95
    Bw[i] = f2bf((n < N_LIN) ? Wlin[n * K_LIN + tm * 3 + jm] : 0.0f);
  }
  if (i < N_PAD) biasp[i] = (i < N_LIN) ? blin[i] : 0.0f;
}

// ---------- kernel 2: LSTM, 4 lanes per chain, x staged via LDS ----------
// 8 sequential steps reading this lane's chain row from LDS (scalar ds_reads,
// immediate offsets). Compiler schedules read-ahead freely (low reg pressure).
__device__ __forceinline__ void steps8(
    const float* __restrict__ xc,   // &xbuf[chain*56]
    float& h0, float& h1, float& h2, float& c,
    const float (&wih)[4][7], const float (&whh)[4][3], const float (&bias)[4],
    float* hv8)
{
#pragma unroll
  for (int s = 0; s < 8; ++s) {
    float zi = bias[0], zf = bias[1], zg = bias[2], zo = bias[3];
#pragma unroll
    for (int k = 0; k < 7; ++k) {
      const float xv = xc[s * 7 + k];
      zi = fmaf(xv, wih[0][k], zi);
      zf = fmaf(xv, wih[1][k], zf);
      zg = fmaf(xv, wih[2][k], zg);
      zo = fmaf(xv, wih[3][k], zo);
    }
    zi = fmaf(h2, whh[0][2], fmaf(h1, whh[0][1], fmaf(h0, whh[0][0], zi)));
    zf = fmaf(h2, whh[1][2], fmaf(h1, whh[1][1], fmaf(h0, whh[1][0], zf)));
    zg = fmaf(h2, whh[2][2], fmaf(h1, whh[2][1], fmaf(h0, whh[2][0], zg)));
    zo = fmaf(h2, whh[3][2], fmaf(h1, whh[3][1], fmaf(h0, whh[3][0], zo)));
    float ig = sig2(zi);
    float fg = sig2(zf);
    float gg = tanh2(zg);                 // g-row prescaled by 2*log2e
    float og = sig2(zo);
    c = fmaf(fg, c, ig * gg);
    float hv = og * tanh2(c * TWO_LOG2E);
    hv8[s] = hv;
    h0 = qbcast<0>(hv);
    h1 = qbcast<1>(hv);
    h2 = qbcast<2>(hv);
  }
}

__global__ __launch_bounds__(256) void lstm_kernel(
    const float* __restrict__ x,
    const float* __restrict__ Wih, const float* __restrict__ Whh,
    const float* __restrict__ bih, const float* __restrict__ bhh,
    u16* __restrict__ hs)
{
  __shared__ float sW[132];
  // x double-buffer: [2 bufs][64 chains][56 floats] = 28 KB
  __shared__ __align__(16) float xb[2][64 * 56];

  const int tid = threadIdx.x;
  for (int i = tid; i < 132; i += 256) {
    float v; int row;
    if (i < 84)       { v = Wih[i];       row = i / 7; }
    else if (i < 120) { v = Whh[i - 84];  row = (i - 84) / 3; }
    else              { v = bih[i - 120] + bhh[i - 120]; row = i - 120; }
    const int G = row / 3;                 // gate 0..3 (i,f,g,o)
    sW[i] = v * ((G == 2) ? TWO_LOG2E : LOG2E);
  }
  __syncthreads();

  const int j  = tid & 3;
  const int jj = (j < 3) ? j : 2;   // lane 3 mirrors lane 2 (never stores)

  // per-lane weights: 4 gates (i,f,g,o) for unit jj
  float wih[4][7], whh[4][3], bias[4];
#pragma unroll
  for (int G = 0; G < 4; ++G) {
    const int row = G * 3 + jj;
#pragma unroll
    for (int k = 0; k < 7; ++k) wih[G][k] = sW[row * 7 + k];
#pragma unroll
    for (int m = 0; m < 3; ++m) whh[G][m] = sW[84 + row * 3 + m];
    bias[G] = sW[120 + row];
  }
  // pin weights in VGPRs once (forbid remat from LDS inside the loop)
#pragma unroll
  for (int G = 0; G < 4; ++G) {
#pragma unroll
    for (int k = 0; k < 7; ++k) asm volatile("" : "+v"(wih[G][k]));
#pragma unroll
    for (int m = 0; m < 3; ++m) asm volatile("" : "+v"(whh[G][m]));
    asm volatile("" : "+v"(bias[G]));
  }

  // staging role: lane handles chain cs = tid&63, wave w = tid>>6 covers
  // float4-units {w, 4+w, 8+w, 12+w(if w<2)} of the 14-unit (56-float) chunk.
  const int cs = tid & 63;
  const int w  = tid >> 6;
  const int b0 = blockIdx.x * 64;
  const float* gbase = x + (size_t)(b0 + cs) * (T_SEQ * D_IN) + w * 4;

  // compute role: quad (tid>>2) owns chain (tid>>2); lane j handles unit jj
  const int cc = tid >> 2;                 // chain within block, 0..63
  const float* xc0 = &xb[0][cc * 56];
  const float* xc1 = &xb[1][cc * 56];
  float* xw0 = &xb[0][cs * 56 + w * 4];
  float* xw1 = &xb[1][cs * 56 + w * 4];

  const int b = b0 + cc;
  u16* __restrict__ hrow = hs + (size_t)b * K_LIN + jj * T_SEQ;  // j-major

  float h0 = 0.f, h1 = 0.f, h2 = 0.f, c = 0.f;
  float hv8[8];

  // ---- prologue: stage chunk 0 into buf 0 ----
  {
    const float4* gp = (const float4*)gbase;
    float4 g0 = gp[0], g1 = gp[4], g2 = gp[8];
    float4 g3 = {};
    if (w < 2) g3 = gp[12];
    float4* ld = (float4*)xw0;
    ld[0] = g0; ld[4] = g1; ld[8] = g2;
    if (w < 2) ld[12] = g3;
  }
  __syncthreads();

  // ---- main loop: 12 chunks, ping-pong buffers, 1 barrier per chunk ----
#pragma unroll 1
  for (int n2 = 0; n2 < 6; ++n2) {
    const int n = n2 * 2;
    // ---- body A: chunk n (buf0), prefetch chunk n+1 -> buf1 ----
    {
      const float4* gp = (const float4*)(gbase + (n + 1) * 56);
      float4 g0 = gp[0], g1 = gp[4], g2 = gp[8];
      float4 g3 = {};
      if (w < 2) g3 = gp[12];
      steps8(xc0, h0, h1, h2, c, wih, whh, bias, hv8);
      __builtin_amdgcn_sched_barrier(0);   // keep ds_writes after compute
      {
        float4* ld = (float4*)xw1;
        ld[0] = g0; ld[4] = g1; ld[8] = g2;
        if (w < 2) ld[12] = g3;
      }
      if (j < 3) {
        u32 w0_, w1_, w2_, w3_;
        asm("v_cvt_pk_bf16_f32 %0, %1, %2" : "=v"(w0_) : "v"(hv8[0]), "v"(hv8[1]));
        asm("v_cvt_pk_bf16_f32 %0, %1, %2" : "=v"(w1_) : "v"(hv8[2]), "v"(hv8[3]));
        asm("v_cvt_pk_bf16_f32 %0, %1, %2" : "=v"(w2_) : "v"(hv8[4]), "v"(hv8[5]));
        asm("v_cvt_pk_bf16_f32 %0, %1, %2" : "=v"(w3_) : "v"(hv8[6]), "v"(hv8[7]));
        uint4 pkv; pkv.x = w0_; pkv.y = w1_; pkv.z = w2_; pkv.w = w3_;
        *(uint4*)(hrow + n * 8) = pkv;     // 16B, contiguous in t (j-major)
      }
      __syncthreads();
    }
    // ---- body B: chunk n+1 (buf1), prefetch chunk n+2 -> buf0 (if any) ----
    {
      const bool has_next = (n2 < 5);
      float4 g0 = {}, g1 = {}, g2 = {}, g3 = {};
      if (has_next) {
        const float4* gp = (const float4*)(gbase + (n + 2) * 56);
        g0 = gp[0]; g1 = gp[4]; g2 = gp[8];
        if (w < 2) g3 = gp[12];
      }
      steps8(xc1, h0, h1, h2, c, wih, whh, bias, hv8);
      __builtin_amdgcn_sched_barrier(0);
      if (has_next) {
        float4* ld = (float4*)xw0;
        ld[0] = g0; ld[4] = g1; ld[8] = g2;
        if (w < 2) ld[12] = g3;
      }
      if (j < 3) {
        u32 w0_, w1_, w2_, w3_;
        asm("v_cvt_pk_bf16_f32 %0, %1, %2" : "=v"(w0_) : "v"(hv8[0]), "v"(hv8[1]));
        asm("v_cvt_pk_bf16_f32 %0, %1, %2" : "=v"(w1_) : "v"(hv8[2]), "v"(hv8[3]));
        asm("v_cvt_pk_bf16_f32 %0, %1, %2" : "=v"(w2_) : "v"(hv8[4]), "v"(hv8[5]));
        asm("v_cvt_pk_bf16_f32 %0, %1, %2" : "=v"(w3_) : "v"(hv8[6]), "v"(hv8[7]));
        uint4 pkv; pkv.x = w0_; pkv.y = w1_; pkv.z = w2_; pkv.w = w3_;
        *(uint4*)(hrow + (n + 1) * 8) = pkv;
      }
      __syncthreads();
    }
  }
}

// ---------- kernel 3: out = hs(bf16)[32768x288] x Bw^T(bf16)[768x288] + bias ----------
__device__ __forceinline__ void gload16(const u16* g, u16* l) {
  __builtin_amdgcn_global_load_lds(
      (const __attribute__((address_space(1))) void*)g,
      (__attribute__((address_space(3))) void*)l, 16, 0, 0);
}

__global__ __launch_bounds__(256) void gemm_kernel(
    const u16* __restrict__ A, const u16* __restrict__ Bw,
    const float* __restrict__ bias, float* __restrict__ C)
{
  __shared__ u16 As[128 * 32];   // 8KB, row-major [128][32]
  __shared__ u16 Bs[128 * 32];
  const int tid  = threadIdx.x;
  const int lane = tid & 63;
  const int wid  = tid >> 6;
  const int wm = wid >> 1, wn = wid & 1;   // 2x2 waves of 64x64

  // XCD-bijective swizzle (1536 % 8 == 0); consecutive swz share A row-panel
  int bx = blockIdx.x;
  int swz = (bx & 7) * 192 + (bx >> 3);
  const int bm = swz / 6;
  const int bn = swz - bm * 6;
  const size_t m0 = (size_t)bm * 128;
  const int n0 = bn * 128;

  const int ra = tid >> 2;          // row 0..63 within half-tile
  const int ca = (tid & 3) * 8;     // 8 bf16 = 16B per thread
  const u16* ga = A  + (m0 + (size_t)ra) * K_LIN + ca;
  const u16* gb = Bw + (size_t)(n0 + ra) * K_LIN + ca;
  u16* lA = &As[wid * 512];         // wave-uniform base; HW adds lane*16B
  u16* lB = &Bs[wid * 512];

  const int l15 = lane & 15, l4 = lane >> 4;
  const u16* pAf = &As[(wm * 64 + l15) * 32 + l4 * 8];
  const u16* pBf = &Bs[(wn * 64 + l15) * 32 + l4 * 8];

  f32x4 acc[4][4] = {};

  for (int kt = 0; kt < 9; ++kt) {  // K = 288 = 9*32
    const int ko = kt * 32;
    gload16(ga + ko,               lA);
    gload16(ga + 64 * K_LIN + ko,  lA + 2048);
    gload16(gb + ko,               lB);
    gload16(gb + 64 * K_LIN + ko,  lB + 2048);
    __syncthreads();                 // drains vmcnt(0) -> tiles resident
    bf16x8 af[4], bfv[4];
#pragma unroll
    for (int i = 0; i < 4; ++i) af[i]  = *(const bf16x8*)(const void*)(pAf + i * 512);
#pragma unroll
    for (int i = 0; i < 4; ++i) bfv[i] = *(const bf16x8*)(const void*)(pBf + i * 512);
#pragma unroll
    for (int mi = 0; mi < 4; ++mi)
#pragma unroll
      for (int ni = 0; ni < 4; ++ni)
        acc[mi][ni] = __builtin_amdgcn_mfma_f32_16x16x32_bf16(af[mi], bfv[ni], acc[mi][ni], 0, 0, 0);
    __syncthreads();                 // protect LDS before next stage
  }

  float bv[4];
#pragma unroll
  for (int ni = 0; ni < 4; ++ni) bv[ni] = bias[n0 + wn * 64 + ni * 16 + l15];

#pragma unroll
  for (int mi = 0; mi < 4; ++mi) {
#pragma unroll
    for (int ni = 0; ni < 4; ++ni) {
      const int col = n0 + wn * 64 + ni * 16 + l15;
      if (col < N_LIN) {
#pragma unroll
        for (int r = 0; r < 4; ++r) {
          const size_t row = m0 + wm * 64 + mi * 16 + l4 * 4 + r;
          C[row * N_LIN + col] = acc[mi][ni][r] + bv[ni];
        }
      }
    }
  }
}

extern "C" void kernel_launch(void* const* d_in, const int* in_sizes, int n_in,
                              void* d_out, int out_size, void* d_ws, size_t ws_size,
                              hipStream_t stream) {
  const float* x    = (const float*)d_in[0];
  const float* Wih  = (const float*)d_in[1];
  const float* Whh  = (const float*)d_in[2];
  const float* bih  = (const float*)d_in[3];
  const float* bhh  = (const float*)d_in[4];
  const float* Wlin = (const float*)d_in[5];
  const float* blin = (const float*)d_in[6];
  float* out = (float*)d_out;

  // workspace layout (19.3 MB): hs bf16 [32768][288] | Bw bf16 [768][288] | bias f32 [768]
  u16* hs = (u16*)d_ws;
  u16* Bw = (u16*)((char*)d_ws + (size_t)B_TOT * K_LIN * 2);
  float* biasp = (float*)((char*)d_ws + (size_t)B_TOT * K_LIN * 2 + (size_t)N_PAD * K_LIN * 2);

  convert_kernel<<<(N_PAD * K_LIN + 255) / 256, 256, 0, stream>>>(Wlin, blin, Bw, biasp);
  lstm_kernel<<<B_TOT / 64, 256, 0, stream>>>(x, Wih, Whh, bih, bhh, hs);
  gemm_kernel<<<(B_TOT / 128) * (N_PAD / 128), 256, 0, stream>>>(hs, Bw, biasp, out);
}